// Round 4
// baseline (241.418 us; speedup 1.0000x reference)
//
#include <hip/hip_runtime.h>
#include <hip/hip_fp16.h>

// Volume: [B=2, X=128, Y=128, Z=128, C=1] fp32, grid: [B, N=2^21, 3] in [0,1].
// Output: [B, N, 1] fp32 trilinear samples.
// image flat index = b*2^21 + x*2^14 + y*2^7 + z  (z fastest).
//
// R4: corner-cube record (16B/voxel, all 8 corners) -> ONE 16B gather/sample.
// R6: ILP=4 sampler: flat at 77 us, same 3.6 TB/s TCC fill rate, VALU 4.9%
//     -> random-64B L2-fill throughput ceiling; ws 33.5 MB/batch vs 4 MB
//     L2/XCD -> 87% miss, ~195 MB refill traffic. Only lever: locality.
// R7: counting sort into 32 buckets = (batch, 8-plane x-slab). Slab records
//     = 2.1 MB -> fits one XCD L2. Payload 12B {idx21, base21, zeroflag,
//     wx/wy/wz 16b quantized} (quant err ~1e-5 << 0.0156 budget; integral
//     coords carry zero-flag -> exact 0 = reference). Sampler pins bucket k
//     to XCD k%8 (blockIdx%8 round-robin), 4 phase-sequential buckets/XCD
//     -> active ws/XCD ~2.1 MB -> gathers become L2 hits at the 12 TB/s
//     request rate R3 demonstrated. Fallback to R4 path if ws too small.

#define TOTAL   (2 * 2097152)   // B * N samples
#define LOG2N   21              // N = 2^21 per batch; VOL = 2^21 voxels too
#define VOL     (128 * 128 * 128)
#define NVOX    (2 * VOL)

#define NBKT    32              // 16 x-slabs x 2 batches
#define CAP     133120          // mean 131072 + 5.8 sigma; overflow -> inline
#define REC_BYTES  ((size_t)NVOX * 16)
#define PAY_BYTES  ((size_t)NBKT * CAP * 12)
#define WS_NEED    (REC_BYTES + PAY_BYTES + 128)

typedef __attribute__((ext_vector_type(4))) float fx4;   // nontemporal-OK

// ---- pre-pass: fp32 volume -> 16B corner-cube records (+ cursor zeroing) --
// rec[b,x,y,z] = { h2(c[x,y,z],c[x,y,z+1]), h2(c[x+1,y,..]),
//                  h2(c[x,y+1,..]), h2(c[x+1,y+1,..]) }   (clamped at 127)
__global__ __launch_bounds__(256)
void ImageWarped_build_rec_kernel(const float* __restrict__ in,
                                  uint4* __restrict__ rec,
                                  unsigned* cursor)
{
    if (cursor && blockIdx.x == 0 && threadIdx.x < NBKT)
        cursor[threadIdx.x] = 0;

    const int idx = blockIdx.x * 256 + threadIdx.x;  // 0..NVOX-1, z fastest
    const int v   = idx & (VOL - 1);
    const int x   = v >> 14;
    const int y   = (v >> 7) & 127;
    const int z   = v & 127;
    const int zp  = min(z + 1, 127);
    const int xo  = (x < 127) ? (1 << 14) : 0;
    const int yo  = (y < 127) ? (1 << 7)  : 0;

    const float* __restrict__ r11 = in + (idx - z);  // row base (incl batch)
    const float* __restrict__ r21 = r11 + xo;
    const float* __restrict__ r12 = r11 + yo;
    const float* __restrict__ r22 = r21 + yo;

    union { __half2 h; unsigned u; } p0, p1, p2, p3;
    p0.h = __floats2half2_rn(r11[z], r11[zp]);
    p1.h = __floats2half2_rn(r21[z], r21[zp]);
    p2.h = __floats2half2_rn(r12[z], r12[zp]);
    p3.h = __floats2half2_rn(r22[z], r22[zp]);

    rec[idx] = make_uint4(p0.u, p1.u, p2.u, p3.u);   // 16B coalesced store
}

// ---- shared helpers (literal two-weight form == reference) ---------------
struct SampleW { int base; float wx, wx2, wy, wy2, wz, wz2; };

__device__ __forceinline__ SampleW mk_sample(float gx, float gy, float gz)
{
    SampleW s;
    const float xf = fminf(fmaxf(gx * 128.0f, 0.001f), 126.999f);
    const float yf = fminf(fmaxf(gy * 128.0f, 0.001f), 126.999f);
    const float zf = fminf(fmaxf(gz * 128.0f, 0.001f), 126.999f);
    const float x1f = floorf(xf), x2f = ceilf(xf);
    const float y1f = floorf(yf), y2f = ceilf(yf);
    const float z1f = floorf(zf), z2f = ceilf(zf);
    s.wx = xf - x1f; s.wx2 = x2f - xf;
    s.wy = yf - y1f; s.wy2 = y2f - yf;
    s.wz = zf - z1f; s.wz2 = z2f - zf;
    s.base = ((int)x1f << 14) + ((int)y1f << 7) + (int)z1f;
    return s;
}

__device__ __forceinline__ float fold_sample(const uint4 u, const SampleW& s)
{
    union { unsigned u32; __half2 h; } c;
    c.u32 = u.x; const float2 f11 = __half22float2(c.h);
    c.u32 = u.y; const float2 f21 = __half22float2(c.h);
    c.u32 = u.z; const float2 f12 = __half22float2(c.h);
    c.u32 = u.w; const float2 f22 = __half22float2(c.h);
    const float q11 = f11.x * s.wz2 + f11.y * s.wz;
    const float q21 = f21.x * s.wz2 + f21.y * s.wz;
    const float q12 = f12.x * s.wz2 + f12.y * s.wz;
    const float q22 = f22.x * s.wz2 + f22.y * s.wz;
    return (q21 * s.wx + q11 * s.wx2) * s.wy2
         + (q22 * s.wx + q12 * s.wx2) * s.wy;
}

// ---- R7 scatter: grid -> 12B payloads bucketed by (batch, x-slab) --------
// payload: a = idx21 | uz[10:0]<<21 ; b = base21 | uz[15:11]<<21 | zero<<31
//          c = ux16 | uy16<<16           (u* = round(w*65535))
__global__ __launch_bounds__(256)
void ImageWarped_scatter_kernel(const float* __restrict__ grid,
                                const uint4* __restrict__ rec,
                                unsigned* __restrict__ pay,
                                unsigned* __restrict__ cursor,
                                float* __restrict__ out)
{
    __shared__ unsigned cnt[NBKT], bbase[NBKT];
    if (threadIdx.x < NBKT) cnt[threadIdx.x] = 0;
    __syncthreads();

    const int t  = blockIdx.x * 256 + threadIdx.x;   // TOTAL/4 threads
    const int i0 = t << 2;
    const int batch = i0 >> LOG2N;                   // all 4 in same batch

    const fx4* gp = (const fx4*)(grid + 3 * (size_t)i0);
    const fx4 ga = __builtin_nontemporal_load(gp + 0);
    const fx4 gb = __builtin_nontemporal_load(gp + 1);
    const fx4 gd = __builtin_nontemporal_load(gp + 2);

    float gxs[4] = {ga.x, ga.w, gb.z, gd.y};
    float gys[4] = {ga.y, gb.x, gb.w, gd.z};
    float gzs[4] = {ga.z, gb.y, gd.x, gd.w};

    unsigned pa[4], pb[4], pc[4], rnk[4];
    int bkt[4];

    #pragma unroll
    for (int j = 0; j < 4; ++j) {
        const float xf = fminf(fmaxf(gxs[j] * 128.0f, 0.001f), 126.999f);
        const float yf = fminf(fmaxf(gys[j] * 128.0f, 0.001f), 126.999f);
        const float zf = fminf(fmaxf(gzs[j] * 128.0f, 0.001f), 126.999f);
        const float x1f = floorf(xf), y1f = floorf(yf), z1f = floorf(zf);
        const bool zero = (xf == x1f) || (yf == y1f) || (zf == z1f);
        const float wx = xf - x1f, wy = yf - y1f, wz = zf - z1f;
        const unsigned ux = zero ? 0u : (unsigned)(wx * 65535.0f + 0.5f);
        const unsigned uy = zero ? 0u : (unsigned)(wy * 65535.0f + 0.5f);
        const unsigned uz = zero ? 0u : (unsigned)(wz * 65535.0f + 0.5f);
        const int ix1 = (int)x1f, iy1 = (int)y1f, iz1 = (int)z1f;
        const unsigned base = (unsigned)((ix1 << 14) | (iy1 << 7) | iz1);
        const unsigned idxl = (unsigned)((i0 + j) & (VOL - 1));
        bkt[j] = ((ix1 >> 3) << 1) | batch;
        pa[j] = idxl | ((uz & 0x7FFu) << 21);
        pb[j] = base | ((uz >> 11) << 21) | (zero ? 0x80000000u : 0u);
        pc[j] = ux | (uy << 16);
        rnk[j] = atomicAdd(&cnt[bkt[j]], 1u);
    }
    __syncthreads();
    if (threadIdx.x < NBKT)
        bbase[threadIdx.x] = atomicAdd(&cursor[threadIdx.x], cnt[threadIdx.x]);
    __syncthreads();

    #pragma unroll
    for (int j = 0; j < 4; ++j) {
        const unsigned pos = bbase[bkt[j]] + rnk[j];
        if (pos < CAP) {
            unsigned* p = pay + ((size_t)bkt[j] * CAP + pos) * 3;
            p[0] = pa[j]; p[1] = pb[j]; p[2] = pc[j];
        } else {
            // statistical overflow (~1e-7): compute inline, exact f32 weights
            const SampleW s = mk_sample(gxs[j], gys[j], gzs[j]);
            const uint4 u = rec[((size_t)batch << LOG2N) + s.base];
            out[i0 + j] = fold_sample(u, s);
        }
    }
}

// ---- R7 sampler: XCD-pinned buckets, phase-sequential slabs --------------
// blockIdx%8 = XCD (empirical round-robin); bucket k = p*8 + XCD, p=0..3.
// Active records/XCD ~= one 2.1 MB slab -> L2-resident gathers.
#define SAMP_BLOCKS 1024        // 8 XCD groups x J=128
__global__ __launch_bounds__(256)
void ImageWarped_sample_sorted_kernel(const uint4* __restrict__ rec,
                                      const unsigned* __restrict__ pay,
                                      const unsigned* __restrict__ cursor,
                                      float* __restrict__ out)
{
    const int c = blockIdx.x & 7;     // XCD pin
    const int q = blockIdx.x >> 3;    // 0..127 chunk index (J=128)

    for (int p = 0; p < 4; ++p) {
        const int k = p * 8 + c;
        const int count = (int)min(cursor[k], (unsigned)CAP);
        const int chunk = (count + 127) >> 7;
        const int start = q * chunk;
        const int end   = min(start + chunk, count);
        const unsigned* __restrict__ pp = pay + (size_t)k * CAP * 3;
        const uint4* __restrict__ rb = rec + ((size_t)(k & 1) << LOG2N);
        float* __restrict__ ob = out + ((size_t)(k & 1) << LOG2N);

        for (int sb = start; sb < end; sb += 1024) {
            #pragma unroll
            for (int u4 = 0; u4 < 4; ++u4) {
                const int s = sb + (u4 << 8) + threadIdx.x;
                if (s < end) {
                    const unsigned a  = pp[3 * s + 0];
                    const unsigned b2 = pp[3 * s + 1];
                    const unsigned c2 = pp[3 * s + 2];
                    const unsigned idxl = a & 0x1FFFFFu;
                    const unsigned base = b2 & 0x1FFFFFu;
                    const unsigned uz = ((a >> 21) & 0x7FFu) | (((b2 >> 21) & 0x1Fu) << 11);
                    const float one = (b2 & 0x80000000u) ? 0.0f : 1.0f;
                    SampleW sw;
                    sw.wx = (float)(c2 & 0xFFFFu) * (1.0f / 65535.0f);
                    sw.wy = (float)(c2 >> 16)     * (1.0f / 65535.0f);
                    sw.wz = (float)uz             * (1.0f / 65535.0f);
                    sw.wx2 = one - sw.wx;
                    sw.wy2 = one - sw.wy;
                    sw.wz2 = one - sw.wz;
                    const uint4 u = rb[base];
                    const float r = fold_sample(u, sw);
                    __builtin_nontemporal_store(r, ob + idxl);
                }
            }
        }
    }
}

// ---- R4/R6 fallback sampler: 4 samples/thread, 16B record gathers --------
__global__ __launch_bounds__(256)
void ImageWarped_trilinear_rec4_kernel(const uint4* __restrict__ rec,
                                       const float* __restrict__ grid,
                                       float* __restrict__ out)
{
    const int batch = blockIdx.x & 1;
    const int g     = (blockIdx.x >> 1) * 256 + threadIdx.x;
    const int i0    = (batch << LOG2N) | (g << 2);

    const fx4* gp = (const fx4*)(grid + 3 * (size_t)i0);
    const fx4 a = __builtin_nontemporal_load(gp + 0);
    const fx4 b = __builtin_nontemporal_load(gp + 1);
    const fx4 d = __builtin_nontemporal_load(gp + 2);

    const uint4* __restrict__ rb = rec + ((size_t)batch << LOG2N);

    const SampleW s0 = mk_sample(a.x, a.y, a.z);
    const SampleW s1 = mk_sample(a.w, b.x, b.y);
    const SampleW s2 = mk_sample(b.z, b.w, d.x);
    const SampleW s3 = mk_sample(d.y, d.z, d.w);

    const uint4 u0 = rb[s0.base];
    const uint4 u1 = rb[s1.base];
    const uint4 u2 = rb[s2.base];
    const uint4 u3 = rb[s3.base];

    fx4 r;
    r.x = fold_sample(u0, s0);
    r.y = fold_sample(u1, s1);
    r.z = fold_sample(u2, s2);
    r.w = fold_sample(u3, s3);
    __builtin_nontemporal_store(r, (fx4*)(out + i0));
}

// ---- R3 fallback: fp16 volume + z-pair gathers ---------------------------
__global__ __launch_bounds__(256)
void ImageWarped_cvt_fp16_kernel(const float* __restrict__ in,
                                 __half* __restrict__ out)
{
    const int i = blockIdx.x * 256 + threadIdx.x;
    const float4 v = ((const float4*)in)[i];
    union { __half2 h2[2]; uint2 u; } p;
    p.h2[0] = __floats2half2_rn(v.x, v.y);
    p.h2[1] = __floats2half2_rn(v.z, v.w);
    ((uint2*)out)[i] = p.u;
}

__global__ __launch_bounds__(256)
void ImageWarped_trilinear_h2_kernel(const __half* __restrict__ image,
                                     const float* __restrict__ grid,
                                     float* __restrict__ out)
{
    const int batch = blockIdx.x & 1;
    const int s     = (blockIdx.x >> 1) * 256 + threadIdx.x;
    const int i     = (batch << LOG2N) | s;

    const float gx = grid[3 * i + 0];
    const float gy = grid[3 * i + 1];
    const float gz = grid[3 * i + 2];

    const __half* __restrict__ img = image + ((size_t)batch << LOG2N);

    const float xf = fminf(fmaxf(gx * 128.0f, 0.001f), 126.999f);
    const float yf = fminf(fmaxf(gy * 128.0f, 0.001f), 126.999f);
    const float zf = fminf(fmaxf(gz * 128.0f, 0.001f), 126.999f);

    const float x1f = floorf(xf), x2f = ceilf(xf);
    const float y1f = floorf(yf), y2f = ceilf(yf);
    const float z1f = floorf(zf), z2f = ceilf(zf);

    const float wx  = xf - x1f, wx2 = x2f - xf;
    const float wy  = yf - y1f, wy2 = y2f - yf;
    const float wz  = zf - z1f, wz2 = z2f - zf;

    const int ix1 = (int)x1f, ix2 = (int)x2f;
    const int iy1 = (int)y1f, iy2 = (int)y2f;
    const int iz1 = (int)z1f;

    const int bx1 = ix1 << 14, bx2 = ix2 << 14;
    const int by1 = iy1 << 7,  by2 = iy2 << 7;

    const int ze = min(iz1 & ~1, 124);
    const int sh = (iz1 - ze) << 4;

    const float  ww  = wz2, wwz = wz;
    auto zfetch = [&](int off) -> float {
        const uint2 u = *(const uint2*)(img + off + ze);
        unsigned long long w = ((unsigned long long)u.y << 32) | u.x;
        w >>= sh;
        union { unsigned int u32; __half2 h; } c;
        c.u32 = (unsigned int)w;
        const float2 f = __half22float2(c.h);
        return f.x * ww + f.y * wwz;
    };

    const float q11 = zfetch(bx1 + by1);
    const float q21 = zfetch(bx2 + by1);
    const float q12 = zfetch(bx1 + by2);
    const float q22 = zfetch(bx2 + by2);

    out[i] = (q21 * wx + q11 * wx2) * wy2
           + (q22 * wx + q12 * wx2) * wy;
}

// ---- last-resort fallback (fp32 gathers, no ws) --------------------------
__global__ __launch_bounds__(256)
void ImageWarped_trilinear_f_kernel(const float* __restrict__ image,
                                    const float* __restrict__ grid,
                                    float* __restrict__ out)
{
    const int i = blockIdx.x * 256 + threadIdx.x;
    if (i >= TOTAL) return;

    const float gx = grid[3 * i + 0];
    const float gy = grid[3 * i + 1];
    const float gz = grid[3 * i + 2];

    const int b = i >> LOG2N;
    const float* __restrict__ img = image + (size_t)b * VOL;

    const SampleW s = mk_sample(gx, gy, gz);
    const int iz1 = s.base & 127;
    const int iz2 = iz1 + (s.wz > 0.0f || s.wz2 > 0.0f ? (s.wz2 == 0.0f && s.wz == 0.0f ? 0 : 1) : 0);
    // recompute corners directly (literal form)
    const int bx1 = s.base & ~0x3FFF;            // not used; keep simple below
    (void)bx1; (void)iz2;

    const float xf = fminf(fmaxf(gx * 128.0f, 0.001f), 126.999f);
    const float yf = fminf(fmaxf(gy * 128.0f, 0.001f), 126.999f);
    const float zf = fminf(fmaxf(gz * 128.0f, 0.001f), 126.999f);
    const float x1f = floorf(xf), x2f = ceilf(xf);
    const float y1f = floorf(yf), y2f = ceilf(yf);
    const float z1f = floorf(zf), z2f = ceilf(zf);
    const float wx  = xf - x1f, wx2 = x2f - xf;
    const float wy  = yf - y1f, wy2 = y2f - yf;
    const float wz  = zf - z1f, wz2 = z2f - zf;
    const int ix1 = (int)x1f, ix2 = (int)x2f;
    const int iy1 = (int)y1f, iy2 = (int)y2f;
    const int jz1 = (int)z1f, jz2 = (int)z2f;
    const int cx1 = ix1 << 14, cx2 = ix2 << 14;
    const int cy1 = iy1 << 7,  cy2 = iy2 << 7;

    const float c111 = img[cx1 + cy1 + jz1];
    const float c211 = img[cx2 + cy1 + jz1];
    const float c121 = img[cx1 + cy2 + jz1];
    const float c221 = img[cx2 + cy2 + jz1];
    const float c112 = img[cx1 + cy1 + jz2];
    const float c212 = img[cx2 + cy1 + jz2];
    const float c122 = img[cx1 + cy2 + jz2];
    const float c222 = img[cx2 + cy2 + jz2];

    const float lerp_y1 = (c211 * wx + c111 * wx2) * wy2
                        + (c221 * wx + c121 * wx2) * wy;
    const float lerp_y2 = (c212 * wx + c112 * wx2) * wy2
                        + (c222 * wx + c122 * wx2) * wy;

    out[i] = lerp_y2 * wz + lerp_y1 * wz2;
}

extern "C" void kernel_launch(void* const* d_in, const int* in_sizes, int n_in,
                              void* d_out, int out_size, void* d_ws, size_t ws_size,
                              hipStream_t stream)
{
    const float* image = (const float*)d_in[0];  // [2,128,128,128,1] fp32
    const float* grid  = (const float*)d_in[1];  // [2,2097152,3]     fp32
    float* out = (float*)d_out;                  // [2,2097152,1]     fp32

    if (ws_size >= WS_NEED) {                    // ~118.3 MB: sort path
        uint4*    rec    = (uint4*)d_ws;
        unsigned* pay    = (unsigned*)((char*)d_ws + REC_BYTES);
        unsigned* cursor = (unsigned*)((char*)d_ws + REC_BYTES + PAY_BYTES);
        ImageWarped_build_rec_kernel<<<NVOX / 256, 256, 0, stream>>>(image, rec, cursor);
        ImageWarped_scatter_kernel<<<TOTAL / 4 / 256, 256, 0, stream>>>(grid, rec, pay, cursor, out);
        ImageWarped_sample_sorted_kernel<<<SAMP_BLOCKS, 256, 0, stream>>>(rec, pay, cursor, out);
    } else if (ws_size >= REC_BYTES) {           // 67.1 MB: R4 path
        uint4* rec = (uint4*)d_ws;
        ImageWarped_build_rec_kernel<<<NVOX / 256, 256, 0, stream>>>(image, rec, nullptr);
        ImageWarped_trilinear_rec4_kernel<<<TOTAL / 4 / 256, 256, 0, stream>>>(rec, grid, out);
    } else if (ws_size >= (size_t)NVOX * sizeof(__half)) {  // 8.4 MB: R3
        __half* img16 = (__half*)d_ws;
        ImageWarped_cvt_fp16_kernel<<<NVOX / 4 / 256, 256, 0, stream>>>(image, img16);
        ImageWarped_trilinear_h2_kernel<<<(TOTAL + 255) / 256, 256, 0, stream>>>(img16, grid, out);
    } else {
        ImageWarped_trilinear_f_kernel<<<(TOTAL + 255) / 256, 256, 0, stream>>>(image, grid, out);
    }
}